// Round 9
// baseline (190.741 us; speedup 1.0000x reference)
//
#include <hip/hip_runtime.h>
#include <hip/hip_bf16.h>

// ---------------------------------------------------------------------------
// EnhancedGNN: 2-layer GCN + linear head + sigmoid.
// R9: gather re-shaped to 16 lanes/edge x 4 edges/pass with uint2 (4-feature)
//     loads — 4x fewer VMEM instructions, amortized addressing; butterfly
//     combine. Partition stage packed to 4 B/edge (src | dstLow<<17).
//     CSR build (LDS-privatized), MFMA GEMMs, bf16 features as R8.
// ---------------------------------------------------------------------------

#define EPB 4096      // edges per partition/count block
#define NBMAX 512     // max buckets (n/256) handled by the fast path

typedef __attribute__((ext_vector_type(8))) short bf16x8;
typedef __attribute__((ext_vector_type(4))) float f32x4;

__device__ __forceinline__ unsigned short f2b(float f) {   // fp32->bf16 RNE
    unsigned u = __builtin_bit_cast(unsigned, f);
    u += 0x7fffu + ((u >> 16) & 1u);
    return (unsigned short)(u >> 16);
}
__device__ __forceinline__ float b2f(unsigned short h) {
    unsigned u = (unsigned)h << 16;
    return __builtin_bit_cast(float, u);
}
__device__ __forceinline__ float blo(unsigned u) {         // low bf16 of dword
    return __builtin_bit_cast(float, u << 16);
}
__device__ __forceinline__ float bhi(unsigned u) {         // high bf16 of dword
    return __builtin_bit_cast(float, u & 0xffff0000u);
}

// ---------------- CSR build ----------------

// Per-block LDS histogram over coarse buckets (node>>8), tiny global merge.
__global__ __launch_bounds__(256) void bcount_k(
    const int* __restrict__ dst, int* __restrict__ bucket_cnt, int E, int nbuckets) {
    __shared__ int lh[NBMAX];
    int t = threadIdx.x;
    for (int i = t; i < nbuckets; i += 256) lh[i] = 0;
    __syncthreads();
    int e0 = blockIdx.x * EPB;
    int cnt = min(EPB, E - e0);
    for (int i = t; i < cnt; i += 256) atomicAdd(&lh[dst[e0 + i] >> 8], 1);
    __syncthreads();
    for (int i = t; i < nbuckets; i += 256)
        if (lh[i]) atomicAdd(&bucket_cnt[i], lh[i]);
}

// Single-block exclusive scan of bucket counts -> bucket_base[0..nb], base[nb]=E.
__global__ __launch_bounds__(512) void bscan_k(
    const int* __restrict__ cnt, int* __restrict__ base, int nb) {
    __shared__ int s[512];
    int t = threadIdx.x;
    int v = (t < nb) ? cnt[t] : 0;
    s[t] = v; __syncthreads();
    #pragma unroll
    for (int off = 1; off < 512; off <<= 1) {
        int u = (t >= off) ? s[t - off] : 0;
        __syncthreads();
        s[t] += u;
        __syncthreads();
    }
    if (t < nb) base[t] = s[t] - v;
    if (t == nb - 1) base[nb] = s[t];
}

__global__ void bucket_init_k(const int* __restrict__ bucket_base, int* __restrict__ bucket_cur, int nbuckets) {
    int b = blockIdx.x * blockDim.x + threadIdx.x;
    if (b < nbuckets) bucket_cur[b] = bucket_base[b];
}

// Partition edges into dst-bucket-clustered staging. Packed: src | dstLow<<17.
__global__ __launch_bounds__(256) void partition_k(
    const int* __restrict__ src, const int* __restrict__ dst,
    int* __restrict__ bucket_cur, int* __restrict__ stage, int E, int nbuckets) {
    __shared__ int ls[EPB];
    __shared__ int ld[EPB];
    __shared__ int lhist[NBMAX];
    __shared__ int lbase[NBMAX];
    int e0 = blockIdx.x * EPB;
    int cnt = min(EPB, E - e0);
    int t = threadIdx.x;
    for (int i = t; i < cnt; i += 256) { ls[i] = src[e0 + i]; ld[i] = dst[e0 + i]; }
    for (int b = t; b < nbuckets; b += 256) lhist[b] = 0;
    __syncthreads();
    for (int i = t; i < cnt; i += 256) atomicAdd(&lhist[ld[i] >> 8], 1);
    __syncthreads();
    for (int b = t; b < nbuckets; b += 256) {
        int c = lhist[b];
        lbase[b] = (c > 0) ? atomicAdd(&bucket_cur[b], c) : 0;
        lhist[b] = 0;
    }
    __syncthreads();
    for (int i = t; i < cnt; i += 256) {
        int d  = ld[i];
        int b  = d >> 8;
        int off = atomicAdd(&lhist[b], 1);
        stage[lbase[b] + off] = ls[i] | ((d & 255) << 17);
    }
}

// One block per bucket: per-node LDS hist + scan -> row_start, dis, placement.
__global__ __launch_bounds__(256) void bucket_place_k(
    const int* __restrict__ stage, const int* __restrict__ bucket_base,
    int* __restrict__ row_start, float* __restrict__ dis,
    int* __restrict__ csr_src, int n, int nbuckets) {
    __shared__ int lh[256];
    __shared__ int ss[256];
    __shared__ int lcur[256];
    int b = blockIdx.x;
    int t = threadIdx.x;
    int ebeg = bucket_base[b], eend = bucket_base[b + 1];
    int node0 = b << 8;

    lh[t] = 0;
    __syncthreads();
    for (int e = ebeg + t; e < eend; e += 256)
        atomicAdd(&lh[(stage[e] >> 17) & 255], 1);
    __syncthreads();

    int cnt = lh[t];
    ss[t] = cnt;
    __syncthreads();
    #pragma unroll
    for (int off = 1; off < 256; off <<= 1) {
        int u = (t >= off) ? ss[t - off] : 0;
        __syncthreads();
        ss[t] += u;
        __syncthreads();
    }
    int excl = ss[t] - cnt;
    int node = node0 + t;
    if (node < n) {
        row_start[node] = ebeg + excl;
        dis[node] = rsqrtf((float)cnt + 1.0f);
    }
    lcur[t] = ebeg + excl;
    if (b == nbuckets - 1 && t == 0) row_start[n] = eend;
    __syncthreads();

    for (int e = ebeg + t; e < eend; e += 256) {
        int p = stage[e];
        int pos = atomicAdd(&lcur[(p >> 17) & 255], 1);
        csr_src[pos] = p & 0x1FFFF;
    }
}

// ---------------- W -> MFMA B-fragment layout (bf16) ----------------
__global__ void wfrag_k(const float* __restrict__ W1, const float* __restrict__ W2,
                        unsigned short* __restrict__ fw1, unsigned short* __restrict__ fw2) {
    int gid = blockIdx.x * blockDim.x + threadIdx.x;
    if (gid < 8192) {
        int f = gid >> 9, rem = gid & 511;
        int l = rem >> 3, i = rem & 7;
        int ks = f >> 2, ct = f & 3;
        int k = ks * 32 + ((l >> 4) << 3) + i;
        int c = ct * 16 + (l & 15);
        fw1[gid] = f2b(W1[k * 64 + c]);
    } else if (gid < 8192 + 4096) {
        int g = gid - 8192;
        int f = g >> 9, rem = g & 511;
        int l = rem >> 3, i = rem & 7;
        int ks = f >> 2, ct = f & 3;
        int k = ks * 32 + ((l >> 4) << 3) + i;
        int c = ct * 16 + (l & 15);
        fw2[g] = f2b(W2[k * 64 + c]);
    }
}

// ---------------- MFMA GEMM: Y[r,:] = bf16( dis[r] * (X[r,:] @ W) ) ----------
template <int K, bool BF16IN>
__global__ __launch_bounds__(256) void mfma_gemm_k(
    const void* __restrict__ Xv, const unsigned short* __restrict__ FW,
    const float* __restrict__ dis, unsigned short* __restrict__ Y, int n) {
    constexpr int KS = K / 32;
    int wave   = (int)((blockIdx.x * blockDim.x + threadIdx.x) >> 6);
    int lane   = threadIdx.x & 63;
    int nwaves = (int)((gridDim.x * blockDim.x) >> 6);
    int ntiles = n >> 4;

    bf16x8 bfrag[KS][4];
    #pragma unroll
    for (int ks = 0; ks < KS; ++ks)
        #pragma unroll
        for (int ct = 0; ct < 4; ++ct)
            bfrag[ks][ct] = *reinterpret_cast<const bf16x8*>(FW + ((ks * 4 + ct) << 9) + (lane << 3));

    int rb = lane & 15;
    int kb = (lane >> 4) << 3;

    for (int tile = wave; tile < ntiles; tile += nwaves) {
        int row = (tile << 4) + rb;
        f32x4 acc[4];
        #pragma unroll
        for (int ct = 0; ct < 4; ++ct) acc[ct] = (f32x4){0.f, 0.f, 0.f, 0.f};

        #pragma unroll
        for (int ks = 0; ks < KS; ++ks) {
            bf16x8 af;
            if (BF16IN) {
                af = *reinterpret_cast<const bf16x8*>(
                    (const unsigned short*)Xv + (size_t)row * K + ks * 32 + kb);
            } else {
                const float* p = (const float*)Xv + (size_t)row * K + ks * 32 + kb;
                float4 u = *reinterpret_cast<const float4*>(p);
                float4 v = *reinterpret_cast<const float4*>(p + 4);
                af[0] = (short)f2b(u.x); af[1] = (short)f2b(u.y);
                af[2] = (short)f2b(u.z); af[3] = (short)f2b(u.w);
                af[4] = (short)f2b(v.x); af[5] = (short)f2b(v.y);
                af[6] = (short)f2b(v.z); af[7] = (short)f2b(v.w);
            }
            #pragma unroll
            for (int ct = 0; ct < 4; ++ct)
                acc[ct] = __builtin_amdgcn_mfma_f32_16x16x32_bf16(af, bfrag[ks][ct], acc[ct], 0, 0, 0);
        }

        int orow0 = (tile << 4) + ((lane >> 4) << 2);
        int ocol  = lane & 15;
        float dv0 = dis[orow0], dv1 = dis[orow0 + 1], dv2 = dis[orow0 + 2], dv3 = dis[orow0 + 3];
        #pragma unroll
        for (int ct = 0; ct < 4; ++ct) {
            Y[(size_t)(orow0 + 0) * 64 + ct * 16 + ocol] = f2b(acc[ct][0] * dv0);
            Y[(size_t)(orow0 + 1) * 64 + ct * 16 + ocol] = f2b(acc[ct][1] * dv1);
            Y[(size_t)(orow0 + 2) * 64 + ct * 16 + ocol] = f2b(acc[ct][2] * dv2);
            Y[(size_t)(orow0 + 3) * 64 + ct * 16 + ocol] = f2b(acc[ct][3] * dv3);
        }
    }

    for (int r = (ntiles << 4) + wave; r < n; r += nwaves) {
        float a = 0.f;
        int c = lane;
        for (int k = 0; k < K; ++k) {
            float xv = BF16IN ? b2f(((const unsigned short*)Xv)[(size_t)r * K + k])
                              : ((const float*)Xv)[(size_t)r * K + k];
            int f  = (k >> 5) * 4 + (c >> 4);
            int lf = (c & 15) + (((k & 31) >> 3) << 4);
            int i  = k & 7;
            a = fmaf(xv, b2f(FW[(f << 9) + (lf << 3) + i]), a);
        }
        Y[(size_t)r * 64 + c] = f2b(a * dis[r]);
    }
}

// ---------------- CSR gather aggregation (one wave per node) ----------------
// 16 lanes/edge x 4 edges/pass; each lane loads uint2 = 4 bf16 features.
// Window of 64 edge ids loaded coalesced, edge id picked via variable shfl.
// MODE 0: h16 = bf16(relu(dd*acc + b))          (layer 1, bf16 out for gemm2)
// MODE 1: out = sigmoid(dot(dd*acc + b, Wl)+bl) (layer 2 + head fused)
template <int MODE>
__global__ __launch_bounds__(256) void gather_k(
    const int* __restrict__ row_start, const int* __restrict__ csr_src,
    const float* __restrict__ dis, const unsigned short* __restrict__ tp,
    const float* __restrict__ b, const float* __restrict__ Wl,
    const float* __restrict__ bl, void* __restrict__ outbuf, int n) {
    int node = (int)((blockIdx.x * blockDim.x + threadIdx.x) >> 6);
    int lane = threadIdx.x & 63;
    if (node >= n) return;
    int eo = lane >> 4;        // edge slot within a pass (0..3)
    int fq = lane & 15;        // feature quad: features 4*fq .. 4*fq+3
    int beg = row_start[node], end = row_start[node + 1];
    float dd = dis[node];

    float a0 = 0.f, a1 = 0.f, a2 = 0.f, a3 = 0.f;
    if (eo == 0) {             // self term once (pre-scaled rows)
        uint2 u = *reinterpret_cast<const uint2*>(tp + (size_t)node * 64 + fq * 4);
        a0 = blo(u.x); a1 = bhi(u.x); a2 = blo(u.y); a3 = bhi(u.y);
    }

    for (int base = beg; base < end; base += 64) {
        int rem = end - base;
        int cnt = rem < 64 ? rem : 64;
        int idx = (lane < cnt) ? csr_src[base + lane] : 0;   // coalesced window
        for (int j = 0; j < cnt; j += 4) {
            int s = __shfl(idx, j + eo);                     // per-lane edge pick
            if (j + eo < cnt) {
                uint2 u = *reinterpret_cast<const uint2*>(tp + (size_t)s * 64 + fq * 4);
                a0 += blo(u.x); a1 += bhi(u.x);
                a2 += blo(u.y); a3 += bhi(u.y);
            }
        }
    }

    // combine the 4 edge slots (all lanes end with full sums)
    #pragma unroll
    for (int m = 16; m <= 32; m <<= 1) {
        a0 += __shfl_xor(a0, m); a1 += __shfl_xor(a1, m);
        a2 += __shfl_xor(a2, m); a3 += __shfl_xor(a3, m);
    }

    int f0 = fq << 2;
    float4 bv = *reinterpret_cast<const float4*>(b + f0);
    float r0 = fmaf(dd, a0, bv.x), r1 = fmaf(dd, a1, bv.y);
    float r2 = fmaf(dd, a2, bv.z), r3 = fmaf(dd, a3, bv.w);

    if (MODE == 0) {
        if (eo == 0) {
            unsigned p0 = (unsigned)f2b(fmaxf(r0, 0.f)) | ((unsigned)f2b(fmaxf(r1, 0.f)) << 16);
            unsigned p1 = (unsigned)f2b(fmaxf(r2, 0.f)) | ((unsigned)f2b(fmaxf(r3, 0.f)) << 16);
            *reinterpret_cast<uint2*>((unsigned short*)outbuf + (size_t)node * 64 + f0) =
                make_uint2(p0, p1);
        }
    } else {
        float4 wv = *reinterpret_cast<const float4*>(Wl + f0);
        float v = r0 * wv.x + r1 * wv.y + r2 * wv.z + r3 * wv.w;
        #pragma unroll
        for (int m = 1; m <= 8; m <<= 1) v += __shfl_xor(v, m);
        if (lane == 0) ((float*)outbuf)[node] = 1.f / (1.f + expf(-(v + bl[0])));
    }
}

// ---------------- fallback kernels (only if ws too small / shape odd) --------

__global__ void relu_k(float* __restrict__ p, long long m) {
    long long i = (long long)blockIdx.x * blockDim.x + threadIdx.x;
    if (i < m) p[i] = fmaxf(p[i], 0.f);
}
__global__ void deg_init_k(float* __restrict__ deg, int n) {
    int i = blockIdx.x * blockDim.x + threadIdx.x;
    if (i < n) deg[i] = 1.0f;
}
__global__ void deg_edges_k(const int* __restrict__ dst, float* __restrict__ deg, int E) {
    int e = blockIdx.x * blockDim.x + threadIdx.x;
    if (e < E) atomicAdd(&deg[dst[e]], 1.0f);
}
__global__ void dis_k(float* __restrict__ deg, int n) {
    int i = blockIdx.x * blockDim.x + threadIdx.x;
    if (i < n) deg[i] = rsqrtf(deg[i]);
}
__global__ void init_agg_k(const float* __restrict__ t, const float* __restrict__ dis,
                           const float* __restrict__ b, float* __restrict__ agg, int n) {
    int idx = blockIdx.x * blockDim.x + threadIdx.x;
    if (idx >= n * 64) return;
    int i = idx >> 6, jj = idx & 63;
    float ds = dis[i];
    agg[idx] = ds * ds * t[idx] + b[jj];
}
__global__ __launch_bounds__(256) void agg_edges_k(
    const int* __restrict__ src, const int* __restrict__ dst,
    const float* __restrict__ dis, const float* __restrict__ t,
    float* __restrict__ agg, int E) {
    int e    = (int)((blockIdx.x * blockDim.x + threadIdx.x) >> 6);
    int lane = threadIdx.x & 63;
    if (e >= E) return;
    int s = src[e], d = dst[e];
    float w = dis[s] * dis[d];
    atomicAdd(&agg[(size_t)d * 64 + lane], w * t[(size_t)s * 64 + lane]);
}
__global__ __launch_bounds__(256) void final_k(
    const float* __restrict__ agg, const float* __restrict__ Wl,
    const float* __restrict__ bl, float* __restrict__ out, int n) {
    int node = (int)((blockIdx.x * blockDim.x + threadIdx.x) >> 6);
    int lane = threadIdx.x & 63;
    if (node >= n) return;
    float v = agg[(size_t)node * 64 + lane] * Wl[lane];
    #pragma unroll
    for (int m = 32; m >= 1; m >>= 1) v += __shfl_xor(v, m);
    if (lane == 0) out[node] = 1.f / (1.f + expf(-(v + bl[0])));
}
template <int K>
__global__ __launch_bounds__(256) void gemm_rows4_k(
    const float* __restrict__ X, const float* __restrict__ W,
    float* __restrict__ Y, int n) {
    __shared__ float Ws[K * 64];
    for (int t = threadIdx.x; t < K * 64; t += blockDim.x) Ws[t] = W[t];
    __syncthreads();
    int wave   = (int)((blockIdx.x * blockDim.x + threadIdx.x) >> 6);
    int lane   = threadIdx.x & 63;
    int nwaves = (int)((gridDim.x * blockDim.x) >> 6);
    for (int r = wave; r < n; r += nwaves) {
        const float* xr = X + (size_t)r * K;
        float acc = 0.f;
        for (int k = 0; k < K; k += 4) {
            float4 a = *reinterpret_cast<const float4*>(xr + k);
            acc = fmaf(a.x, Ws[(k + 0) * 64 + lane], acc);
            acc = fmaf(a.y, Ws[(k + 1) * 64 + lane], acc);
            acc = fmaf(a.z, Ws[(k + 2) * 64 + lane], acc);
            acc = fmaf(a.w, Ws[(k + 3) * 64 + lane], acc);
        }
        Y[(size_t)r * 64 + lane] = acc;
    }
}

// ---------------------------------------------------------------------------

extern "C" void kernel_launch(void* const* d_in, const int* in_sizes, int n_in,
                              void* d_out, int out_size, void* d_ws, size_t ws_size,
                              hipStream_t stream) {
    const float* x  = (const float*)d_in[0];
    const int*   ei = (const int*)d_in[1];
    const float* W1 = (const float*)d_in[2];
    const float* b1 = (const float*)d_in[3];
    const float* W2 = (const float*)d_in[4];
    const float* b2 = (const float*)d_in[5];
    const float* Wl = (const float*)d_in[6];
    const float* bl = (const float*)d_in[7];
    float* out = (float*)d_out;

    const int n = in_sizes[0] / 128;      // 100000
    const int E = in_sizes[1] / 2;        // 1600000
    const int* src = ei;
    const int* dst = ei + E;

    const int B = 256;
    dim3 blk(B);
    auto align512 = [](size_t v) { return (v + 511) & ~(size_t)511; };

    // workspace layout
    char* ws = (char*)d_ws;
    size_t off = 0;
    float*          dis     = (float*)(ws + off); off = align512(off + (size_t)n * 4);
    int*            row_st  = (int*)  (ws + off); off = align512(off + (size_t)(n + 1) * 4);
    int*            bcnt    = (int*)  (ws + off); off = align512(off + (size_t)(NBMAX + 1) * 4);
    int*            bbase   = (int*)  (ws + off); off = align512(off + (size_t)(NBMAX + 1) * 4);
    int*            bcur    = (int*)  (ws + off); off = align512(off + (size_t)NBMAX * 4);
    int*            csr_src = (int*)  (ws + off); off = align512(off + (size_t)E * 4);
    unsigned short* bufA16  = (unsigned short*)(ws + off); off = align512(off + (size_t)n * 64 * 2);
    unsigned short* h16     = (unsigned short*)(ws + off); off = align512(off + (size_t)n * 64 * 2);
    int*            stage   = (int*)  (ws + off); off = align512(off + (size_t)E * 4);
    unsigned short* fw1     = (unsigned short*)(ws + off); off = align512(off + 8192 * 2);
    unsigned short* fw2     = (unsigned short*)(ws + off); off = align512(off + 4096 * 2);
    size_t need_csr = off;

    const int nbuckets = (n + 255) >> 8;
    const int nebl = (E + EPB - 1) / EPB;   // edge blocks

    if (ws_size >= need_csr && (n & 15) == 0 && nbuckets <= NBMAX && n <= (1 << 17)) {
        // ---- W fragment packing (tiny) ----
        wfrag_k<<<48, blk, 0, stream>>>(W1, W2, fw1, fw2);

        // ---- CSR build (LDS-privatized, no hot global atomics) ----
        hipMemsetAsync(bcnt, 0, (size_t)(NBMAX + 1) * 4, stream);
        bcount_k<<<nebl, blk, 0, stream>>>(dst, bcnt, E, nbuckets);
        bscan_k<<<1, 512, 0, stream>>>(bcnt, bbase, nbuckets);
        bucket_init_k<<<(nbuckets + B - 1) / B, blk, 0, stream>>>(bbase, bcur, nbuckets);
        partition_k<<<nebl, blk, 0, stream>>>(src, dst, bcur, stage, E, nbuckets);
        bucket_place_k<<<nbuckets, blk, 0, stream>>>(stage, bbase, row_st, dis, csr_src, n, nbuckets);

        int gemm_blocks = ((n >> 4) + 3) / 4;   // one wave per 16-row tile

        // ---- layer 1 ----
        mfma_gemm_k<128, false><<<gemm_blocks, blk, 0, stream>>>(x, fw1, dis, bufA16, n);
        gather_k<0><<<((size_t)n * 64 + B - 1) / B, blk, 0, stream>>>(
            row_st, csr_src, dis, bufA16, b1, Wl, bl, h16, n);

        // ---- layer 2 + head ----
        mfma_gemm_k<64, true><<<gemm_blocks, blk, 0, stream>>>(h16, fw2, dis, bufA16, n);
        gather_k<1><<<((size_t)n * 64 + B - 1) / B, blk, 0, stream>>>(
            row_st, csr_src, dis, bufA16, b2, Wl, bl, out, n);
    } else {
        // ---- fallback: atomic scatter, fp32 GEMM ----
        size_t o2 = 0;
        float* dis2 = (float*)(ws + o2); o2 = align512(o2 + (size_t)n * 4);
        float* bA   = (float*)(ws + o2); o2 += (size_t)n * 64 * 4;
        float* bB   = (float*)(ws + o2);

        deg_init_k<<<(n + B - 1) / B, blk, 0, stream>>>(dis2, n);
        deg_edges_k<<<(E + B - 1) / B, blk, 0, stream>>>(dst, dis2, E);
        dis_k<<<(n + B - 1) / B, blk, 0, stream>>>(dis2, n);

        gemm_rows4_k<128><<<2048, blk, 0, stream>>>(x, W1, bA, n);
        init_agg_k<<<((size_t)n * 64 + B - 1) / B, blk, 0, stream>>>(bA, dis2, b1, bB, n);
        agg_edges_k<<<(E + 3) / 4, blk, 0, stream>>>(src, dst, dis2, bA, bB, E);
        relu_k<<<((size_t)n * 64 + B - 1) / B, blk, 0, stream>>>(bB, (long long)n * 64);

        gemm_rows4_k<64><<<2048, blk, 0, stream>>>(bB, W2, bA, n);
        init_agg_k<<<((size_t)n * 64 + B - 1) / B, blk, 0, stream>>>(bA, dis2, b2, bB, n);
        agg_edges_k<<<(E + 3) / 4, blk, 0, stream>>>(src, dst, dis2, bA, bB, E);

        final_k<<<(n + 3) / 4, blk, 0, stream>>>(bB, Wl, bl, out, n);
    }
}

// Round 10
// 137.332 us; speedup vs baseline: 1.3889x; 1.3889x over previous
//
#include <hip/hip_runtime.h>
#include <hip/hip_bf16.h>

// ---------------------------------------------------------------------------
// EnhancedGNN: 2-layer GCN + linear head + sigmoid.
// R10: (a) gather1 reverted to R8 shape (64 lanes/edge, 8 accs — proven 52us);
//      (b) ALGEBRAIC: head dot pushed through layer-2 aggregation:
//          z[r] = dis[r]*dot(t2[r],Wl) computed in gemm2 epilogue (butterfly,
//          no t2 buffer); out[d] = sigmoid(dis[d]*(z[d]+sum_N z[s]) + c0),
//          c0 = dot(b2,Wl)+bl. Gather2: 128 B/edge -> 4 B/edge (L2-resident).
//      (c) bcnt zeroing + c0 folded into wfrag_k; bcur init into bscan_k.
// ---------------------------------------------------------------------------

#define EPB 4096      // edges per partition/count block
#define NBMAX 512     // max buckets (n/256) handled by the fast path

typedef __attribute__((ext_vector_type(8))) short bf16x8;
typedef __attribute__((ext_vector_type(4))) float f32x4;

__device__ __forceinline__ unsigned short f2b(float f) {   // fp32->bf16 RNE
    unsigned u = __builtin_bit_cast(unsigned, f);
    u += 0x7fffu + ((u >> 16) & 1u);
    return (unsigned short)(u >> 16);
}
__device__ __forceinline__ float b2f(unsigned short h) {
    unsigned u = (unsigned)h << 16;
    return __builtin_bit_cast(float, u);
}

// ---------------- CSR build ----------------

__global__ __launch_bounds__(256) void bcount_k(
    const int* __restrict__ dst, int* __restrict__ bucket_cnt, int E, int nbuckets) {
    __shared__ int lh[NBMAX];
    int t = threadIdx.x;
    for (int i = t; i < nbuckets; i += 256) lh[i] = 0;
    __syncthreads();
    int e0 = blockIdx.x * EPB;
    int cnt = min(EPB, E - e0);
    for (int i = t; i < cnt; i += 256) atomicAdd(&lh[dst[e0 + i] >> 8], 1);
    __syncthreads();
    for (int i = t; i < nbuckets; i += 256)
        if (lh[i]) atomicAdd(&bucket_cnt[i], lh[i]);
}

// Exclusive scan of bucket counts -> base[0..nb] (base[nb]=E) and cur[] copy.
__global__ __launch_bounds__(512) void bscan_k(
    const int* __restrict__ cnt, int* __restrict__ base, int* __restrict__ cur, int nb) {
    __shared__ int s[512];
    int t = threadIdx.x;
    int v = (t < nb) ? cnt[t] : 0;
    s[t] = v; __syncthreads();
    #pragma unroll
    for (int off = 1; off < 512; off <<= 1) {
        int u = (t >= off) ? s[t - off] : 0;
        __syncthreads();
        s[t] += u;
        __syncthreads();
    }
    if (t < nb) { int e = s[t] - v; base[t] = e; cur[t] = e; }
    if (t == nb - 1) base[nb] = s[t];
}

// Partition edges into dst-bucket-clustered staging. Packed: src | dstLow<<17.
__global__ __launch_bounds__(256) void partition_k(
    const int* __restrict__ src, const int* __restrict__ dst,
    int* __restrict__ bucket_cur, int* __restrict__ stage, int E, int nbuckets) {
    __shared__ int ls[EPB];
    __shared__ int ld[EPB];
    __shared__ int lhist[NBMAX];
    __shared__ int lbase[NBMAX];
    int e0 = blockIdx.x * EPB;
    int cnt = min(EPB, E - e0);
    int t = threadIdx.x;
    for (int i = t; i < cnt; i += 256) { ls[i] = src[e0 + i]; ld[i] = dst[e0 + i]; }
    for (int b = t; b < nbuckets; b += 256) lhist[b] = 0;
    __syncthreads();
    for (int i = t; i < cnt; i += 256) atomicAdd(&lhist[ld[i] >> 8], 1);
    __syncthreads();
    for (int b = t; b < nbuckets; b += 256) {
        int c = lhist[b];
        lbase[b] = (c > 0) ? atomicAdd(&bucket_cur[b], c) : 0;
        lhist[b] = 0;
    }
    __syncthreads();
    for (int i = t; i < cnt; i += 256) {
        int d  = ld[i];
        int b  = d >> 8;
        int off = atomicAdd(&lhist[b], 1);
        stage[lbase[b] + off] = ls[i] | ((d & 255) << 17);
    }
}

// One block per bucket: per-node LDS hist + scan -> row_start, dis, placement.
__global__ __launch_bounds__(256) void bucket_place_k(
    const int* __restrict__ stage, const int* __restrict__ bucket_base,
    int* __restrict__ row_start, float* __restrict__ dis,
    int* __restrict__ csr_src, int n, int nbuckets) {
    __shared__ int lh[256];
    __shared__ int ss[256];
    __shared__ int lcur[256];
    int b = blockIdx.x;
    int t = threadIdx.x;
    int ebeg = bucket_base[b], eend = bucket_base[b + 1];
    int node0 = b << 8;

    lh[t] = 0;
    __syncthreads();
    for (int e = ebeg + t; e < eend; e += 256)
        atomicAdd(&lh[(stage[e] >> 17) & 255], 1);
    __syncthreads();

    int cnt = lh[t];
    ss[t] = cnt;
    __syncthreads();
    #pragma unroll
    for (int off = 1; off < 256; off <<= 1) {
        int u = (t >= off) ? ss[t - off] : 0;
        __syncthreads();
        ss[t] += u;
        __syncthreads();
    }
    int excl = ss[t] - cnt;
    int node = node0 + t;
    if (node < n) {
        row_start[node] = ebeg + excl;
        dis[node] = rsqrtf((float)cnt + 1.0f);
    }
    lcur[t] = ebeg + excl;
    if (b == nbuckets - 1 && t == 0) row_start[n] = eend;
    __syncthreads();

    for (int e = ebeg + t; e < eend; e += 256) {
        int p = stage[e];
        int pos = atomicAdd(&lcur[(p >> 17) & 255], 1);
        csr_src[pos] = p & 0x1FFFF;
    }
}

// ---------------- W -> MFMA B-fragment layout + bcnt zero + c0 ----------------
__global__ void wfrag_k(const float* __restrict__ W1, const float* __restrict__ W2,
                        unsigned short* __restrict__ fw1, unsigned short* __restrict__ fw2,
                        const float* __restrict__ b2, const float* __restrict__ Wl,
                        const float* __restrict__ bl, float* __restrict__ c0,
                        int* __restrict__ bcnt) {
    int gid = blockIdx.x * blockDim.x + threadIdx.x;
    if (gid <= NBMAX) bcnt[gid] = 0;                       // zero bucket counters
    if (blockIdx.x == 0 && threadIdx.x < 64) {             // c0 = dot(b2,Wl)+bl
        float v = b2[threadIdx.x] * Wl[threadIdx.x];
        #pragma unroll
        for (int m = 32; m >= 1; m >>= 1) v += __shfl_xor(v, m);
        if (threadIdx.x == 0) c0[0] = v + bl[0];
    }
    if (gid < 8192) {
        int f = gid >> 9, rem = gid & 511;
        int l = rem >> 3, i = rem & 7;
        int ks = f >> 2, ct = f & 3;
        int k = ks * 32 + ((l >> 4) << 3) + i;
        int c = ct * 16 + (l & 15);
        fw1[gid] = f2b(W1[k * 64 + c]);
    } else if (gid < 8192 + 4096) {
        int g = gid - 8192;
        int f = g >> 9, rem = g & 511;
        int l = rem >> 3, i = rem & 7;
        int ks = f >> 2, ct = f & 3;
        int k = ks * 32 + ((l >> 4) << 3) + i;
        int c = ct * 16 + (l & 15);
        fw2[g] = f2b(W2[k * 64 + c]);
    }
}

// ---------------- MFMA GEMM ----------------
// EPI=0: Y[r,:] = bf16( dis[r] * (X[r,:] @ W) )     (feeds the feature gather)
// EPI=1: z[r]   = dis[r] * dot( X[r,:] @ W , Wl )   (head folded; no Y writes)
template <int K, bool BF16IN, int EPI>
__global__ __launch_bounds__(256) void mfma_gemm_k(
    const void* __restrict__ Xv, const unsigned short* __restrict__ FW,
    const float* __restrict__ dis, unsigned short* __restrict__ Y,
    const float* __restrict__ Wl, float* __restrict__ z, int n) {
    constexpr int KS = K / 32;
    int wave   = (int)((blockIdx.x * blockDim.x + threadIdx.x) >> 6);
    int lane   = threadIdx.x & 63;
    int nwaves = (int)((gridDim.x * blockDim.x) >> 6);
    int ntiles = n >> 4;

    bf16x8 bfrag[KS][4];
    #pragma unroll
    for (int ks = 0; ks < KS; ++ks)
        #pragma unroll
        for (int ct = 0; ct < 4; ++ct)
            bfrag[ks][ct] = *reinterpret_cast<const bf16x8*>(FW + ((ks * 4 + ct) << 9) + (lane << 3));

    int rb = lane & 15;
    int kb = (lane >> 4) << 3;

    float wl0, wl1, wl2, wl3;
    if (EPI == 1) {
        int fq = lane & 15;
        wl0 = Wl[fq]; wl1 = Wl[16 + fq]; wl2 = Wl[32 + fq]; wl3 = Wl[48 + fq];
    }

    for (int tile = wave; tile < ntiles; tile += nwaves) {
        int row = (tile << 4) + rb;
        f32x4 acc[4];
        #pragma unroll
        for (int ct = 0; ct < 4; ++ct) acc[ct] = (f32x4){0.f, 0.f, 0.f, 0.f};

        #pragma unroll
        for (int ks = 0; ks < KS; ++ks) {
            bf16x8 af;
            if (BF16IN) {
                af = *reinterpret_cast<const bf16x8*>(
                    (const unsigned short*)Xv + (size_t)row * K + ks * 32 + kb);
            } else {
                const float* p = (const float*)Xv + (size_t)row * K + ks * 32 + kb;
                float4 u = *reinterpret_cast<const float4*>(p);
                float4 v = *reinterpret_cast<const float4*>(p + 4);
                af[0] = (short)f2b(u.x); af[1] = (short)f2b(u.y);
                af[2] = (short)f2b(u.z); af[3] = (short)f2b(u.w);
                af[4] = (short)f2b(v.x); af[5] = (short)f2b(v.y);
                af[6] = (short)f2b(v.z); af[7] = (short)f2b(v.w);
            }
            #pragma unroll
            for (int ct = 0; ct < 4; ++ct)
                acc[ct] = __builtin_amdgcn_mfma_f32_16x16x32_bf16(af, bfrag[ks][ct], acc[ct], 0, 0, 0);
        }

        int orow0 = (tile << 4) + ((lane >> 4) << 2);
        if (EPI == 0) {
            int ocol = lane & 15;
            float dv0 = dis[orow0], dv1 = dis[orow0 + 1], dv2 = dis[orow0 + 2], dv3 = dis[orow0 + 3];
            #pragma unroll
            for (int ct = 0; ct < 4; ++ct) {
                Y[(size_t)(orow0 + 0) * 64 + ct * 16 + ocol] = f2b(acc[ct][0] * dv0);
                Y[(size_t)(orow0 + 1) * 64 + ct * 16 + ocol] = f2b(acc[ct][1] * dv1);
                Y[(size_t)(orow0 + 2) * 64 + ct * 16 + ocol] = f2b(acc[ct][2] * dv2);
                Y[(size_t)(orow0 + 3) * 64 + ct * 16 + ocol] = f2b(acc[ct][3] * dv3);
            }
        } else {
            // per-row dot with Wl: lane partial over its 4 cols, butterfly over
            // the 16-lane group (masks 1,2,4,8 stay in-group), lane fq==0 stores.
            #pragma unroll
            for (int reg = 0; reg < 4; ++reg) {
                float p = acc[0][reg] * wl0 + acc[1][reg] * wl1
                        + acc[2][reg] * wl2 + acc[3][reg] * wl3;
                p += __shfl_xor(p, 1); p += __shfl_xor(p, 2);
                p += __shfl_xor(p, 4); p += __shfl_xor(p, 8);
                if ((lane & 15) == 0) {
                    int row = orow0 + reg;
                    z[row] = p * dis[row];
                }
            }
        }
    }

    if (EPI == 0) {   // tail rows (dead when n%16==0; fast path guarantees it)
        for (int r = (ntiles << 4) + wave; r < n; r += nwaves) {
            float a = 0.f;
            int c = lane;
            for (int k = 0; k < K; ++k) {
                float xv = BF16IN ? b2f(((const unsigned short*)Xv)[(size_t)r * K + k])
                                  : ((const float*)Xv)[(size_t)r * K + k];
                int f  = (k >> 5) * 4 + (c >> 4);
                int lf = (c & 15) + (((k & 31) >> 3) << 4);
                int i  = k & 7;
                a = fmaf(xv, b2f(FW[(f << 9) + (lf << 3) + i]), a);
            }
            Y[(size_t)r * 64 + c] = f2b(a * dis[r]);
        }
    }
}

// ---------------- layer-1 gather (R8 shape: 64 lanes/edge, 8 accs) ----------
__global__ __launch_bounds__(256) void gather_k(
    const int* __restrict__ row_start, const int* __restrict__ csr_src,
    const float* __restrict__ dis, const unsigned short* __restrict__ tp,
    const float* __restrict__ b, unsigned short* __restrict__ outbuf, int n) {
    int node = (int)((blockIdx.x * blockDim.x + threadIdx.x) >> 6);
    int lane = threadIdx.x & 63;
    if (node >= n) return;
    int beg = row_start[node], end = row_start[node + 1];
    float dd = dis[node];
    float a0 = b2f(tp[(size_t)node * 64 + lane]);   // self term (pre-scaled)
    float a1 = 0.f, a2 = 0.f, a3 = 0.f, a4 = 0.f, a5 = 0.f, a6 = 0.f, a7 = 0.f;

    for (int base = beg; base < end; base += 64) {
        int rem = end - base;
        int cnt = rem < 64 ? rem : 64;
        int idx = (lane < cnt) ? csr_src[base + lane] : 0;   // coalesced window
        int j = 0;
        for (; j + 8 <= cnt; j += 8) {
            int s0 = __shfl(idx, j + 0), s1 = __shfl(idx, j + 1);
            int s2 = __shfl(idx, j + 2), s3 = __shfl(idx, j + 3);
            int s4 = __shfl(idx, j + 4), s5 = __shfl(idx, j + 5);
            int s6 = __shfl(idx, j + 6), s7 = __shfl(idx, j + 7);
            a0 += b2f(tp[(size_t)s0 * 64 + lane]);
            a1 += b2f(tp[(size_t)s1 * 64 + lane]);
            a2 += b2f(tp[(size_t)s2 * 64 + lane]);
            a3 += b2f(tp[(size_t)s3 * 64 + lane]);
            a4 += b2f(tp[(size_t)s4 * 64 + lane]);
            a5 += b2f(tp[(size_t)s5 * 64 + lane]);
            a6 += b2f(tp[(size_t)s6 * 64 + lane]);
            a7 += b2f(tp[(size_t)s7 * 64 + lane]);
        }
        if (j + 4 <= cnt) {
            int s0 = __shfl(idx, j + 0), s1 = __shfl(idx, j + 1);
            int s2 = __shfl(idx, j + 2), s3 = __shfl(idx, j + 3);
            a0 += b2f(tp[(size_t)s0 * 64 + lane]);
            a1 += b2f(tp[(size_t)s1 * 64 + lane]);
            a2 += b2f(tp[(size_t)s2 * 64 + lane]);
            a3 += b2f(tp[(size_t)s3 * 64 + lane]);
            j += 4;
        }
        for (; j < cnt; ++j) {
            int s = __shfl(idx, j);
            a4 += b2f(tp[(size_t)s * 64 + lane]);
        }
    }

    float acc = ((a0 + a1) + (a2 + a3)) + ((a4 + a5) + (a6 + a7));
    float r = fmaf(dd, acc, b[lane]);
    outbuf[(size_t)node * 64 + lane] = f2b(fmaxf(r, 0.f));
}

// ---------------- layer-2 scalar gather + sigmoid (head folded) -------------
__global__ __launch_bounds__(256) void gatherz_k(
    const int* __restrict__ row_start, const int* __restrict__ csr_src,
    const float* __restrict__ dis, const float* __restrict__ z,
    const float* __restrict__ c0, float* __restrict__ out, int n) {
    int i = blockIdx.x * blockDim.x + threadIdx.x;
    if (i >= n) return;
    int beg = row_start[i], end = row_start[i + 1];
    float s0 = 0.f, s1 = 0.f, s2 = 0.f, s3 = 0.f;
    int e = beg;
    for (; e + 4 <= end; e += 4) {
        s0 += z[csr_src[e + 0]];
        s1 += z[csr_src[e + 1]];
        s2 += z[csr_src[e + 2]];
        s3 += z[csr_src[e + 3]];
    }
    for (; e < end; ++e) s0 += z[csr_src[e]];
    float v = fmaf(dis[i], z[i] + ((s0 + s1) + (s2 + s3)), c0[0]);
    out[i] = 1.f / (1.f + expf(-v));
}

// ---------------- fallback kernels (only if ws too small / shape odd) --------

__global__ void relu_k(float* __restrict__ p, long long m) {
    long long i = (long long)blockIdx.x * blockDim.x + threadIdx.x;
    if (i < m) p[i] = fmaxf(p[i], 0.f);
}
__global__ void deg_init_k(float* __restrict__ deg, int n) {
    int i = blockIdx.x * blockDim.x + threadIdx.x;
    if (i < n) deg[i] = 1.0f;
}
__global__ void deg_edges_k(const int* __restrict__ dst, float* __restrict__ deg, int E) {
    int e = blockIdx.x * blockDim.x + threadIdx.x;
    if (e < E) atomicAdd(&deg[dst[e]], 1.0f);
}
__global__ void dis_k(float* __restrict__ deg, int n) {
    int i = blockIdx.x * blockDim.x + threadIdx.x;
    if (i < n) deg[i] = rsqrtf(deg[i]);
}
__global__ void init_agg_k(const float* __restrict__ t, const float* __restrict__ dis,
                           const float* __restrict__ b, float* __restrict__ agg, int n) {
    int idx = blockIdx.x * blockDim.x + threadIdx.x;
    if (idx >= n * 64) return;
    int i = idx >> 6, jj = idx & 63;
    float ds = dis[i];
    agg[idx] = ds * ds * t[idx] + b[jj];
}
__global__ __launch_bounds__(256) void agg_edges_k(
    const int* __restrict__ src, const int* __restrict__ dst,
    const float* __restrict__ dis, const float* __restrict__ t,
    float* __restrict__ agg, int E) {
    int e    = (int)((blockIdx.x * blockDim.x + threadIdx.x) >> 6);
    int lane = threadIdx.x & 63;
    if (e >= E) return;
    int s = src[e], d = dst[e];
    float w = dis[s] * dis[d];
    atomicAdd(&agg[(size_t)d * 64 + lane], w * t[(size_t)s * 64 + lane]);
}
__global__ __launch_bounds__(256) void final_k(
    const float* __restrict__ agg, const float* __restrict__ Wl,
    const float* __restrict__ bl, float* __restrict__ out, int n) {
    int node = (int)((blockIdx.x * blockDim.x + threadIdx.x) >> 6);
    int lane = threadIdx.x & 63;
    if (node >= n) return;
    float v = agg[(size_t)node * 64 + lane] * Wl[lane];
    #pragma unroll
    for (int m = 32; m >= 1; m >>= 1) v += __shfl_xor(v, m);
    if (lane == 0) out[node] = 1.f / (1.f + expf(-(v + bl[0])));
}
template <int K>
__global__ __launch_bounds__(256) void gemm_rows4_k(
    const float* __restrict__ X, const float* __restrict__ W,
    float* __restrict__ Y, int n) {
    __shared__ float Ws[K * 64];
    for (int t = threadIdx.x; t < K * 64; t += blockDim.x) Ws[t] = W[t];
    __syncthreads();
    int wave   = (int)((blockIdx.x * blockDim.x + threadIdx.x) >> 6);
    int lane   = threadIdx.x & 63;
    int nwaves = (int)((gridDim.x * blockDim.x) >> 6);
    for (int r = wave; r < n; r += nwaves) {
        const float* xr = X + (size_t)r * K;
        float acc = 0.f;
        for (int k = 0; k < K; k += 4) {
            float4 a = *reinterpret_cast<const float4*>(xr + k);
            acc = fmaf(a.x, Ws[(k + 0) * 64 + lane], acc);
            acc = fmaf(a.y, Ws[(k + 1) * 64 + lane], acc);
            acc = fmaf(a.z, Ws[(k + 2) * 64 + lane], acc);
            acc = fmaf(a.w, Ws[(k + 3) * 64 + lane], acc);
        }
        Y[(size_t)r * 64 + lane] = acc;
    }
}

// ---------------------------------------------------------------------------

extern "C" void kernel_launch(void* const* d_in, const int* in_sizes, int n_in,
                              void* d_out, int out_size, void* d_ws, size_t ws_size,
                              hipStream_t stream) {
    const float* x  = (const float*)d_in[0];
    const int*   ei = (const int*)d_in[1];
    const float* W1 = (const float*)d_in[2];
    const float* b1 = (const float*)d_in[3];
    const float* W2 = (const float*)d_in[4];
    const float* b2 = (const float*)d_in[5];
    const float* Wl = (const float*)d_in[6];
    const float* bl = (const float*)d_in[7];
    float* out = (float*)d_out;

    const int n = in_sizes[0] / 128;      // 100000
    const int E = in_sizes[1] / 2;        // 1600000
    const int* src = ei;
    const int* dst = ei + E;

    const int B = 256;
    dim3 blk(B);
    auto align512 = [](size_t v) { return (v + 511) & ~(size_t)511; };

    // workspace layout
    char* ws = (char*)d_ws;
    size_t off = 0;
    float*          dis     = (float*)(ws + off); off = align512(off + (size_t)n * 4);
    int*            row_st  = (int*)  (ws + off); off = align512(off + (size_t)(n + 1) * 4);
    int*            bcnt    = (int*)  (ws + off); off = align512(off + (size_t)(NBMAX + 1) * 4);
    int*            bbase   = (int*)  (ws + off); off = align512(off + (size_t)(NBMAX + 1) * 4);
    int*            bcur    = (int*)  (ws + off); off = align512(off + (size_t)NBMAX * 4);
    float*          c0      = (float*)(ws + off); off = align512(off + 512);
    float*          zbuf    = (float*)(ws + off); off = align512(off + (size_t)n * 4);
    int*            csr_src = (int*)  (ws + off); off = align512(off + (size_t)E * 4);
    unsigned short* bufA16  = (unsigned short*)(ws + off); off = align512(off + (size_t)n * 64 * 2);
    unsigned short* h16     = (unsigned short*)(ws + off); off = align512(off + (size_t)n * 64 * 2);
    int*            stage   = (int*)  (ws + off); off = align512(off + (size_t)E * 4);
    unsigned short* fw1     = (unsigned short*)(ws + off); off = align512(off + 8192 * 2);
    unsigned short* fw2     = (unsigned short*)(ws + off); off = align512(off + 4096 * 2);
    size_t need_csr = off;

    const int nbuckets = (n + 255) >> 8;
    const int nebl = (E + EPB - 1) / EPB;   // edge blocks

    if (ws_size >= need_csr && (n & 15) == 0 && nbuckets <= NBMAX && n <= (1 << 17)) {
        // ---- W frag pack + bcnt zero + c0 (one small launch) ----
        wfrag_k<<<48, blk, 0, stream>>>(W1, W2, fw1, fw2, b2, Wl, bl, c0, bcnt);

        // ---- CSR build (LDS-privatized, no hot global atomics) ----
        bcount_k<<<nebl, blk, 0, stream>>>(dst, bcnt, E, nbuckets);
        bscan_k<<<1, 512, 0, stream>>>(bcnt, bbase, bcur, nbuckets);
        partition_k<<<nebl, blk, 0, stream>>>(src, dst, bcur, stage, E, nbuckets);
        bucket_place_k<<<nbuckets, blk, 0, stream>>>(stage, bbase, row_st, dis, csr_src, n, nbuckets);

        int gemm_blocks = ((n >> 4) + 3) / 4;   // one wave per 16-row tile

        // ---- layer 1: bufA16 = bf16(dis*(x@W1)); h16 = bf16(relu(agg+b1)) ----
        mfma_gemm_k<128, false, 0><<<gemm_blocks, blk, 0, stream>>>(
            x, fw1, dis, bufA16, Wl, zbuf, n);
        gather_k<<<((size_t)n * 64 + B - 1) / B, blk, 0, stream>>>(
            row_st, csr_src, dis, bufA16, b1, h16, n);

        // ---- layer 2 + head: z = dis*(h16@W2)·Wl ; out = sigmoid(...) ----
        mfma_gemm_k<64, true, 1><<<gemm_blocks, blk, 0, stream>>>(
            h16, fw2, dis, (unsigned short*)nullptr, Wl, zbuf, n);
        gatherz_k<<<(n + B - 1) / B, blk, 0, stream>>>(
            row_st, csr_src, dis, zbuf, c0, out, n);
    } else {
        // ---- fallback: atomic scatter, fp32 GEMM ----
        size_t o2 = 0;
        float* dis2 = (float*)(ws + o2); o2 = align512(o2 + (size_t)n * 4);
        float* bA   = (float*)(ws + o2); o2 += (size_t)n * 64 * 4;
        float* bB   = (float*)(ws + o2);

        deg_init_k<<<(n + B - 1) / B, blk, 0, stream>>>(dis2, n);
        deg_edges_k<<<(E + B - 1) / B, blk, 0, stream>>>(dst, dis2, E);
        dis_k<<<(n + B - 1) / B, blk, 0, stream>>>(dis2, n);

        gemm_rows4_k<128><<<2048, blk, 0, stream>>>(x, W1, bA, n);
        init_agg_k<<<((size_t)n * 64 + B - 1) / B, blk, 0, stream>>>(bA, dis2, b1, bB, n);
        agg_edges_k<<<(E + 3) / 4, blk, 0, stream>>>(src, dst, dis2, bA, bB, E);
        relu_k<<<((size_t)n * 64 + B - 1) / B, blk, 0, stream>>>(bB, (long long)n * 64);

        gemm_rows4_k<64><<<2048, blk, 0, stream>>>(bB, W2, bA, n);
        init_agg_k<<<((size_t)n * 64 + B - 1) / B, blk, 0, stream>>>(bA, dis2, b2, bB, n);
        agg_edges_k<<<(E + 3) / 4, blk, 0, stream>>>(src, dst, dis2, bA, bB, E);

        final_k<<<(n + 3) / 4, blk, 0, stream>>>(bB, Wl, bl, out, n);
    }
}

// Round 11
// 132.602 us; speedup vs baseline: 1.4384x; 1.0357x over previous
//
#include <hip/hip_runtime.h>
#include <hip/hip_bf16.h>

// ---------------------------------------------------------------------------
// EnhancedGNN: 2-layer GCN + linear head + sigmoid.
// R11: second algebraic fold — w2l = W2 @ Wl precomputed, so
//      z[r] = dis[r] * dot(relu(agg1[r]+b1), w2l) is computed in gather1's
//      epilogue (h1 never materialized, gemm2 eliminated entirely).
//      out[d] = sigmoid(dis[d]*(z[d]+sum_N z[s]) + c0), c0 = dot(b2,Wl)+bl.
//      CSR build (LDS-privatized two-phase), MFMA gemm1, bf16 features as R10.
// ---------------------------------------------------------------------------

#define EPB 4096      // edges per partition/count block
#define NBMAX 512     // max buckets (n/256) handled by the fast path

typedef __attribute__((ext_vector_type(8))) short bf16x8;
typedef __attribute__((ext_vector_type(4))) float f32x4;

__device__ __forceinline__ unsigned short f2b(float f) {   // fp32->bf16 RNE
    unsigned u = __builtin_bit_cast(unsigned, f);
    u += 0x7fffu + ((u >> 16) & 1u);
    return (unsigned short)(u >> 16);
}
__device__ __forceinline__ float b2f(unsigned short h) {
    unsigned u = (unsigned)h << 16;
    return __builtin_bit_cast(float, u);
}

// ---------------- CSR build ----------------

__global__ __launch_bounds__(256) void bcount_k(
    const int* __restrict__ dst, int* __restrict__ bucket_cnt, int E, int nbuckets) {
    __shared__ int lh[NBMAX];
    int t = threadIdx.x;
    for (int i = t; i < nbuckets; i += 256) lh[i] = 0;
    __syncthreads();
    int e0 = blockIdx.x * EPB;
    int cnt = min(EPB, E - e0);
    for (int i = t; i < cnt; i += 256) atomicAdd(&lh[dst[e0 + i] >> 8], 1);
    __syncthreads();
    for (int i = t; i < nbuckets; i += 256)
        if (lh[i]) atomicAdd(&bucket_cnt[i], lh[i]);
}

// Exclusive scan of bucket counts -> base[0..nb] (base[nb]=E) and cur[] copy.
__global__ __launch_bounds__(512) void bscan_k(
    const int* __restrict__ cnt, int* __restrict__ base, int* __restrict__ cur, int nb) {
    __shared__ int s[512];
    int t = threadIdx.x;
    int v = (t < nb) ? cnt[t] : 0;
    s[t] = v; __syncthreads();
    #pragma unroll
    for (int off = 1; off < 512; off <<= 1) {
        int u = (t >= off) ? s[t - off] : 0;
        __syncthreads();
        s[t] += u;
        __syncthreads();
    }
    if (t < nb) { int e = s[t] - v; base[t] = e; cur[t] = e; }
    if (t == nb - 1) base[nb] = s[t];
}

// Partition edges into dst-bucket-clustered staging. Packed: src | dstLow<<17.
__global__ __launch_bounds__(256) void partition_k(
    const int* __restrict__ src, const int* __restrict__ dst,
    int* __restrict__ bucket_cur, int* __restrict__ stage, int E, int nbuckets) {
    __shared__ int ls[EPB];
    __shared__ int ld[EPB];
    __shared__ int lhist[NBMAX];
    __shared__ int lbase[NBMAX];
    int e0 = blockIdx.x * EPB;
    int cnt = min(EPB, E - e0);
    int t = threadIdx.x;
    for (int i = t; i < cnt; i += 256) { ls[i] = src[e0 + i]; ld[i] = dst[e0 + i]; }
    for (int b = t; b < nbuckets; b += 256) lhist[b] = 0;
    __syncthreads();
    for (int i = t; i < cnt; i += 256) atomicAdd(&lhist[ld[i] >> 8], 1);
    __syncthreads();
    for (int b = t; b < nbuckets; b += 256) {
        int c = lhist[b];
        lbase[b] = (c > 0) ? atomicAdd(&bucket_cur[b], c) : 0;
        lhist[b] = 0;
    }
    __syncthreads();
    for (int i = t; i < cnt; i += 256) {
        int d  = ld[i];
        int b  = d >> 8;
        int off = atomicAdd(&lhist[b], 1);
        stage[lbase[b] + off] = ls[i] | ((d & 255) << 17);
    }
}

// One block per bucket: per-node LDS hist + scan -> row_start, dis, placement.
__global__ __launch_bounds__(256) void bucket_place_k(
    const int* __restrict__ stage, const int* __restrict__ bucket_base,
    int* __restrict__ row_start, float* __restrict__ dis,
    int* __restrict__ csr_src, int n, int nbuckets) {
    __shared__ int lh[256];
    __shared__ int ss[256];
    __shared__ int lcur[256];
    int b = blockIdx.x;
    int t = threadIdx.x;
    int ebeg = bucket_base[b], eend = bucket_base[b + 1];
    int node0 = b << 8;

    lh[t] = 0;
    __syncthreads();
    for (int e = ebeg + t; e < eend; e += 256)
        atomicAdd(&lh[(stage[e] >> 17) & 255], 1);
    __syncthreads();

    int cnt = lh[t];
    ss[t] = cnt;
    __syncthreads();
    #pragma unroll
    for (int off = 1; off < 256; off <<= 1) {
        int u = (t >= off) ? ss[t - off] : 0;
        __syncthreads();
        ss[t] += u;
        __syncthreads();
    }
    int excl = ss[t] - cnt;
    int node = node0 + t;
    if (node < n) {
        row_start[node] = ebeg + excl;
        dis[node] = rsqrtf((float)cnt + 1.0f);
    }
    lcur[t] = ebeg + excl;
    if (b == nbuckets - 1 && t == 0) row_start[n] = eend;
    __syncthreads();

    for (int e = ebeg + t; e < eend; e += 256) {
        int p = stage[e];
        int pos = atomicAdd(&lcur[(p >> 17) & 255], 1);
        csr_src[pos] = p & 0x1FFFF;
    }
}

// ---------------- W1 frag pack + w2l + c0 + bcnt zero (one small launch) -----
__global__ void wfrag_k(const float* __restrict__ W1, const float* __restrict__ W2,
                        unsigned short* __restrict__ fw1, float* __restrict__ w2l,
                        const float* __restrict__ b2, const float* __restrict__ Wl,
                        const float* __restrict__ bl, float* __restrict__ c0,
                        int* __restrict__ bcnt) {
    int gid = blockIdx.x * blockDim.x + threadIdx.x;
    if (gid <= NBMAX) bcnt[gid] = 0;                       // zero bucket counters
    if (blockIdx.x == 0 && threadIdx.x < 64) {             // c0 = dot(b2,Wl)+bl
        float v = b2[threadIdx.x] * Wl[threadIdx.x];
        #pragma unroll
        for (int m = 32; m >= 1; m >>= 1) v += __shfl_xor(v, m);
        if (threadIdx.x == 0) c0[0] = v + bl[0];
    }
    if (blockIdx.x == 1 && threadIdx.x < 64) {             // w2l = W2 @ Wl
        int k = threadIdx.x;
        float s = 0.f;
        #pragma unroll 8
        for (int j = 0; j < 64; ++j) s = fmaf(W2[k * 64 + j], Wl[j], s);
        w2l[k] = s;
    }
    if (gid < 8192) {                                      // W1 B-fragments
        int f = gid >> 9, rem = gid & 511;
        int l = rem >> 3, i = rem & 7;
        int ks = f >> 2, ct = f & 3;
        int k = ks * 32 + ((l >> 4) << 3) + i;
        int c = ct * 16 + (l & 15);
        fw1[gid] = f2b(W1[k * 64 + c]);
    }
}

// ---------------- MFMA GEMM1: Y[r,:] = bf16( dis[r] * (x[r,:] @ W1) ) --------
template <int K>
__global__ __launch_bounds__(256) void mfma_gemm_k(
    const float* __restrict__ X, const unsigned short* __restrict__ FW,
    const float* __restrict__ dis, unsigned short* __restrict__ Y, int n) {
    constexpr int KS = K / 32;
    int wave   = (int)((blockIdx.x * blockDim.x + threadIdx.x) >> 6);
    int lane   = threadIdx.x & 63;
    int nwaves = (int)((gridDim.x * blockDim.x) >> 6);
    int ntiles = n >> 4;

    bf16x8 bfrag[KS][4];
    #pragma unroll
    for (int ks = 0; ks < KS; ++ks)
        #pragma unroll
        for (int ct = 0; ct < 4; ++ct)
            bfrag[ks][ct] = *reinterpret_cast<const bf16x8*>(FW + ((ks * 4 + ct) << 9) + (lane << 3));

    int rb = lane & 15;
    int kb = (lane >> 4) << 3;

    for (int tile = wave; tile < ntiles; tile += nwaves) {
        int row = (tile << 4) + rb;
        f32x4 acc[4];
        #pragma unroll
        for (int ct = 0; ct < 4; ++ct) acc[ct] = (f32x4){0.f, 0.f, 0.f, 0.f};

        #pragma unroll
        for (int ks = 0; ks < KS; ++ks) {
            const float* p = X + (size_t)row * K + ks * 32 + kb;
            float4 u = *reinterpret_cast<const float4*>(p);
            float4 v = *reinterpret_cast<const float4*>(p + 4);
            bf16x8 af;
            af[0] = (short)f2b(u.x); af[1] = (short)f2b(u.y);
            af[2] = (short)f2b(u.z); af[3] = (short)f2b(u.w);
            af[4] = (short)f2b(v.x); af[5] = (short)f2b(v.y);
            af[6] = (short)f2b(v.z); af[7] = (short)f2b(v.w);
            #pragma unroll
            for (int ct = 0; ct < 4; ++ct)
                acc[ct] = __builtin_amdgcn_mfma_f32_16x16x32_bf16(af, bfrag[ks][ct], acc[ct], 0, 0, 0);
        }

        int orow0 = (tile << 4) + ((lane >> 4) << 2);
        int ocol  = lane & 15;
        float dv0 = dis[orow0], dv1 = dis[orow0 + 1], dv2 = dis[orow0 + 2], dv3 = dis[orow0 + 3];
        #pragma unroll
        for (int ct = 0; ct < 4; ++ct) {
            Y[(size_t)(orow0 + 0) * 64 + ct * 16 + ocol] = f2b(acc[ct][0] * dv0);
            Y[(size_t)(orow0 + 1) * 64 + ct * 16 + ocol] = f2b(acc[ct][1] * dv1);
            Y[(size_t)(orow0 + 2) * 64 + ct * 16 + ocol] = f2b(acc[ct][2] * dv2);
            Y[(size_t)(orow0 + 3) * 64 + ct * 16 + ocol] = f2b(acc[ct][3] * dv3);
        }
    }
}

// ---------------- fused gather1 + (relu, W2@Wl dot) -> z ---------------------
// Per node: agg = tp[node] + sum_{s in N} tp[s]  (tp rows pre-scaled by dis);
// h1 = relu(dd*agg + b1)  (fp32, registers only);
// z[node] = dd * dot(h1, w2l)  (butterfly reduce; single float store).
__global__ __launch_bounds__(256) void gather_k(
    const int* __restrict__ row_start, const int* __restrict__ csr_src,
    const float* __restrict__ dis, const unsigned short* __restrict__ tp,
    const float* __restrict__ b, const float* __restrict__ w2l,
    float* __restrict__ z, int n) {
    int node = (int)((blockIdx.x * blockDim.x + threadIdx.x) >> 6);
    int lane = threadIdx.x & 63;
    if (node >= n) return;
    int beg = row_start[node], end = row_start[node + 1];
    float dd = dis[node];
    float a0 = b2f(tp[(size_t)node * 64 + lane]);   // self term (pre-scaled)
    float a1 = 0.f, a2 = 0.f, a3 = 0.f, a4 = 0.f, a5 = 0.f, a6 = 0.f, a7 = 0.f;

    for (int base = beg; base < end; base += 64) {
        int rem = end - base;
        int cnt = rem < 64 ? rem : 64;
        int idx = (lane < cnt) ? csr_src[base + lane] : 0;   // coalesced window
        int j = 0;
        for (; j + 8 <= cnt; j += 8) {
            int s0 = __shfl(idx, j + 0), s1 = __shfl(idx, j + 1);
            int s2 = __shfl(idx, j + 2), s3 = __shfl(idx, j + 3);
            int s4 = __shfl(idx, j + 4), s5 = __shfl(idx, j + 5);
            int s6 = __shfl(idx, j + 6), s7 = __shfl(idx, j + 7);
            a0 += b2f(tp[(size_t)s0 * 64 + lane]);
            a1 += b2f(tp[(size_t)s1 * 64 + lane]);
            a2 += b2f(tp[(size_t)s2 * 64 + lane]);
            a3 += b2f(tp[(size_t)s3 * 64 + lane]);
            a4 += b2f(tp[(size_t)s4 * 64 + lane]);
            a5 += b2f(tp[(size_t)s5 * 64 + lane]);
            a6 += b2f(tp[(size_t)s6 * 64 + lane]);
            a7 += b2f(tp[(size_t)s7 * 64 + lane]);
        }
        if (j + 4 <= cnt) {
            int s0 = __shfl(idx, j + 0), s1 = __shfl(idx, j + 1);
            int s2 = __shfl(idx, j + 2), s3 = __shfl(idx, j + 3);
            a0 += b2f(tp[(size_t)s0 * 64 + lane]);
            a1 += b2f(tp[(size_t)s1 * 64 + lane]);
            a2 += b2f(tp[(size_t)s2 * 64 + lane]);
            a3 += b2f(tp[(size_t)s3 * 64 + lane]);
            j += 4;
        }
        for (; j < cnt; ++j) {
            int s = __shfl(idx, j);
            a4 += b2f(tp[(size_t)s * 64 + lane]);
        }
    }

    float acc = ((a0 + a1) + (a2 + a3)) + ((a4 + a5) + (a6 + a7));
    float h = fmaxf(fmaf(dd, acc, b[lane]), 0.f);   // h1[node][lane], fp32
    float v = h * w2l[lane];
    #pragma unroll
    for (int m = 32; m >= 1; m >>= 1) v += __shfl_xor(v, m);
    if (lane == 0) z[node] = dd * v;
}

// ---------------- layer-2 scalar gather + sigmoid (head folded) -------------
__global__ __launch_bounds__(256) void gatherz_k(
    const int* __restrict__ row_start, const int* __restrict__ csr_src,
    const float* __restrict__ dis, const float* __restrict__ z,
    const float* __restrict__ c0, float* __restrict__ out, int n) {
    int i = blockIdx.x * blockDim.x + threadIdx.x;
    if (i >= n) return;
    int beg = row_start[i], end = row_start[i + 1];
    float s0 = 0.f, s1 = 0.f, s2 = 0.f, s3 = 0.f;
    int e = beg;
    for (; e + 4 <= end; e += 4) {
        s0 += z[csr_src[e + 0]];
        s1 += z[csr_src[e + 1]];
        s2 += z[csr_src[e + 2]];
        s3 += z[csr_src[e + 3]];
    }
    for (; e < end; ++e) s0 += z[csr_src[e]];
    float v = fmaf(dis[i], z[i] + ((s0 + s1) + (s2 + s3)), c0[0]);
    out[i] = 1.f / (1.f + expf(-v));
}

// ---------------- fallback kernels (only if ws too small / shape odd) --------

__global__ void relu_k(float* __restrict__ p, long long m) {
    long long i = (long long)blockIdx.x * blockDim.x + threadIdx.x;
    if (i < m) p[i] = fmaxf(p[i], 0.f);
}
__global__ void deg_init_k(float* __restrict__ deg, int n) {
    int i = blockIdx.x * blockDim.x + threadIdx.x;
    if (i < n) deg[i] = 1.0f;
}
__global__ void deg_edges_k(const int* __restrict__ dst, float* __restrict__ deg, int E) {
    int e = blockIdx.x * blockDim.x + threadIdx.x;
    if (e < E) atomicAdd(&deg[dst[e]], 1.0f);
}
__global__ void dis_k(float* __restrict__ deg, int n) {
    int i = blockIdx.x * blockDim.x + threadIdx.x;
    if (i < n) deg[i] = rsqrtf(deg[i]);
}
__global__ void init_agg_k(const float* __restrict__ t, const float* __restrict__ dis,
                           const float* __restrict__ b, float* __restrict__ agg, int n) {
    int idx = blockIdx.x * blockDim.x + threadIdx.x;
    if (idx >= n * 64) return;
    int i = idx >> 6, jj = idx & 63;
    float ds = dis[i];
    agg[idx] = ds * ds * t[idx] + b[jj];
}
__global__ __launch_bounds__(256) void agg_edges_k(
    const int* __restrict__ src, const int* __restrict__ dst,
    const float* __restrict__ dis, const float* __restrict__ t,
    float* __restrict__ agg, int E) {
    int e    = (int)((blockIdx.x * blockDim.x + threadIdx.x) >> 6);
    int lane = threadIdx.x & 63;
    if (e >= E) return;
    int s = src[e], d = dst[e];
    float w = dis[s] * dis[d];
    atomicAdd(&agg[(size_t)d * 64 + lane], w * t[(size_t)s * 64 + lane]);
}
__global__ __launch_bounds__(256) void final_k(
    const float* __restrict__ agg, const float* __restrict__ Wl,
    const float* __restrict__ bl, float* __restrict__ out, int n) {
    int node = (int)((blockIdx.x * blockDim.x + threadIdx.x) >> 6);
    int lane = threadIdx.x & 63;
    if (node >= n) return;
    float v = agg[(size_t)node * 64 + lane] * Wl[lane];
    #pragma unroll
    for (int m = 32; m >= 1; m >>= 1) v += __shfl_xor(v, m);
    if (lane == 0) out[node] = 1.f / (1.f + expf(-(v + bl[0])));
}
template <int K>
__global__ __launch_bounds__(256) void gemm_rows4_k(
    const float* __restrict__ X, const float* __restrict__ W,
    float* __restrict__ Y, int n) {
    __shared__ float Ws[K * 64];
    for (int t = threadIdx.x; t < K * 64; t += blockDim.x) Ws[t] = W[t];
    __syncthreads();
    int wave   = (int)((blockIdx.x * blockDim.x + threadIdx.x) >> 6);
    int lane   = threadIdx.x & 63;
    int nwaves = (int)((gridDim.x * blockDim.x) >> 6);
    for (int r = wave; r < n; r += nwaves) {
        const float* xr = X + (size_t)r * K;
        float acc = 0.f;
        for (int k = 0; k < K; k += 4) {
            float4 a = *reinterpret_cast<const float4*>(xr + k);
            acc = fmaf(a.x, Ws[(k + 0) * 64 + lane], acc);
            acc = fmaf(a.y, Ws[(k + 1) * 64 + lane], acc);
            acc = fmaf(a.z, Ws[(k + 2) * 64 + lane], acc);
            acc = fmaf(a.w, Ws[(k + 3) * 64 + lane], acc);
        }
        Y[(size_t)r * 64 + lane] = acc;
    }
}

// ---------------------------------------------------------------------------

extern "C" void kernel_launch(void* const* d_in, const int* in_sizes, int n_in,
                              void* d_out, int out_size, void* d_ws, size_t ws_size,
                              hipStream_t stream) {
    const float* x  = (const float*)d_in[0];
    const int*   ei = (const int*)d_in[1];
    const float* W1 = (const float*)d_in[2];
    const float* b1 = (const float*)d_in[3];
    const float* W2 = (const float*)d_in[4];
    const float* b2 = (const float*)d_in[5];
    const float* Wl = (const float*)d_in[6];
    const float* bl = (const float*)d_in[7];
    float* out = (float*)d_out;

    const int n = in_sizes[0] / 128;      // 100000
    const int E = in_sizes[1] / 2;        // 1600000
    const int* src = ei;
    const int* dst = ei + E;

    const int B = 256;
    dim3 blk(B);
    auto align512 = [](size_t v) { return (v + 511) & ~(size_t)511; };

    // workspace layout
    char* ws = (char*)d_ws;
    size_t off = 0;
    float*          dis     = (float*)(ws + off); off = align512(off + (size_t)n * 4);
    int*            row_st  = (int*)  (ws + off); off = align512(off + (size_t)(n + 1) * 4);
    int*            bcnt    = (int*)  (ws + off); off = align512(off + (size_t)(NBMAX + 1) * 4);
    int*            bbase   = (int*)  (ws + off); off = align512(off + (size_t)(NBMAX + 1) * 4);
    int*            bcur    = (int*)  (ws + off); off = align512(off + (size_t)NBMAX * 4);
    float*          c0      = (float*)(ws + off); off = align512(off + 512);
    float*          w2l     = (float*)(ws + off); off = align512(off + 64 * 4);
    float*          zbuf    = (float*)(ws + off); off = align512(off + (size_t)n * 4);
    int*            csr_src = (int*)  (ws + off); off = align512(off + (size_t)E * 4);
    unsigned short* bufA16  = (unsigned short*)(ws + off); off = align512(off + (size_t)n * 64 * 2);
    int*            stage   = (int*)  (ws + off); off = align512(off + (size_t)E * 4);
    unsigned short* fw1     = (unsigned short*)(ws + off); off = align512(off + 8192 * 2);
    size_t need_csr = off;

    const int nbuckets = (n + 255) >> 8;
    const int nebl = (E + EPB - 1) / EPB;   // edge blocks

    if (ws_size >= need_csr && (n & 15) == 0 && nbuckets <= NBMAX && n <= (1 << 17)) {
        // ---- W1 frag pack + w2l + c0 + bcnt zero (one small launch) ----
        wfrag_k<<<48, blk, 0, stream>>>(W1, W2, fw1, w2l, b2, Wl, bl, c0, bcnt);

        // ---- CSR build (LDS-privatized, no hot global atomics) ----
        bcount_k<<<nebl, blk, 0, stream>>>(dst, bcnt, E, nbuckets);
        bscan_k<<<1, 512, 0, stream>>>(bcnt, bbase, bcur, nbuckets);
        partition_k<<<nebl, blk, 0, stream>>>(src, dst, bcur, stage, E, nbuckets);
        bucket_place_k<<<nbuckets, blk, 0, stream>>>(stage, bbase, row_st, dis, csr_src, n, nbuckets);

        int gemm_blocks = ((n >> 4) + 3) / 4;   // one wave per 16-row tile

        // ---- layer 1 GEMM: bufA16 = bf16(dis * (x @ W1)) ----
        mfma_gemm_k<128><<<gemm_blocks, blk, 0, stream>>>(x, fw1, dis, bufA16, n);

        // ---- fused gather1 + relu + (W2@Wl) dot -> z ----
        gather_k<<<((size_t)n * 64 + B - 1) / B, blk, 0, stream>>>(
            row_st, csr_src, dis, bufA16, b1, w2l, zbuf, n);

        // ---- layer-2 scalar aggregation + sigmoid ----
        gatherz_k<<<(n + B - 1) / B, blk, 0, stream>>>(
            row_st, csr_src, dis, zbuf, c0, out, n);
    } else {
        // ---- fallback: atomic scatter, fp32 GEMM ----
        size_t o2 = 0;
        float* dis2 = (float*)(ws + o2); o2 = align512(o2 + (size_t)n * 4);
        float* bA   = (float*)(ws + o2); o2 += (size_t)n * 64 * 4;
        float* bB   = (float*)(ws + o2);

        deg_init_k<<<(n + B - 1) / B, blk, 0, stream>>>(dis2, n);
        deg_edges_k<<<(E + B - 1) / B, blk, 0, stream>>>(dst, dis2, E);
        dis_k<<<(n + B - 1) / B, blk, 0, stream>>>(dis2, n);

        gemm_rows4_k<128><<<2048, blk, 0, stream>>>(x, W1, bA, n);
        init_agg_k<<<((size_t)n * 64 + B - 1) / B, blk, 0, stream>>>(bA, dis2, b1, bB, n);
        agg_edges_k<<<(E + 3) / 4, blk, 0, stream>>>(src, dst, dis2, bA, bB, E);
        relu_k<<<((size_t)n * 64 + B - 1) / B, blk, 0, stream>>>(bB, (long long)n * 64);

        gemm_rows4_k<64><<<2048, blk, 0, stream>>>(bB, W2, bA, n);
        init_agg_k<<<((size_t)n * 64 + B - 1) / B, blk, 0, stream>>>(bA, dis2, b2, bB, n);
        agg_edges_k<<<(E + 3) / 4, blk, 0, stream>>>(src, dst, dis2, bA, bB, E);

        final_k<<<(n + 3) / 4, blk, 0, stream>>>(bB, Wl, bl, out, n);
    }
}